// Round 1
// baseline (226.190 us; speedup 1.0000x reference)
//
#include <hip/hip_runtime.h>

#define ALPHA 0.2f
#define B_    8
#define N_    2048
#define INF_  128
#define OUTF_ 64
#define LOG2E 1.4426950408889634f

typedef __attribute__((ext_vector_type(8))) short short8;
typedef __attribute__((ext_vector_type(4))) float f32x4;

__device__ __forceinline__ unsigned short f2bf(float f) {
    unsigned int x = __float_as_uint(f);
    return (unsigned short)((x + 0x7fffu + ((x >> 16) & 1u)) >> 16);
}

// Kernel A: x_w = inputs @ W -> xwT (bf16, [B][64][N]) + s1/s2 row scores.
// 32 rows/block, 8 rows/wave. Input rows via wave-uniform SCALAR loads
// (s_load path, no LDS); W column via 1 ds_read_b32 per k (reused 8x).
__global__ __launch_bounds__(256) void prep_kernel(
    const float* __restrict__ inp,    // [B*N, 128] f32
    const float* __restrict__ nodes,  // [B*N, 64]  f32
    const float* __restrict__ Wm,     // [128, 64]  f32
    const float* __restrict__ av,     // [256]      f32
    unsigned short* __restrict__ xwT, // [B][64][N] bf16
    float* __restrict__ s1_out,       // [B*N]
    float* __restrict__ s2_out)       // [B*N]
{
    __shared__ float w_lds[INF_ * OUTF_];                    // 32 KB [k][f]
    __shared__ __align__(16) unsigned short t_lds[64 * 40];  // [f][32+pad] bf16
    const int tid  = threadIdx.x;
    const int wave = tid >> 6, lane = tid & 63;
    const int r0   = blockIdx.x * 32;

    {
        const float4* Wv = (const float4*)Wm;                // 2048 float4
        float4* wd = (float4*)w_lds;
        #pragma unroll
        for (int q = 0; q < 8; q++) wd[tid + q * 256] = Wv[tid + q * 256];
    }
    __syncthreads();

    // force wave-uniformity so row loads take the scalar (SMEM) path
    const int wv = __builtin_amdgcn_readfirstlane(wave);
    const float* __restrict__ rbase = inp + (size_t)(r0 + wv * 8) * INF_;

    float acc0[8] = {0.f,0.f,0.f,0.f,0.f,0.f,0.f,0.f};
    float acc1[8] = {0.f,0.f,0.f,0.f,0.f,0.f,0.f,0.f};
    #pragma unroll 4
    for (int k = 0; k < INF_; k += 2) {
        const float w0 = w_lds[k * OUTF_ + lane];        // stride-1 lanes, no conflict
        const float w1 = w_lds[(k + 1) * OUTF_ + lane];
        #pragma unroll
        for (int rr = 0; rr < 8; rr++) {
            acc0[rr] += rbase[rr * INF_ + k]     * w0;   // scalar-operand FMA
            acc1[rr] += rbase[rr * INF_ + k + 1] * w1;
        }
    }
    float acc[8];
    #pragma unroll
    for (int rr = 0; rr < 8; rr++) acc[rr] = acc0[rr] + acc1[rr];

    const float a1n = av[lane];
    const float a1x = av[64 + lane];
    const float a2n = av[128 + lane];
    const float a2x = av[192 + lane];

    #pragma unroll
    for (int rr = 0; rr < 8; rr++) {
        const int row = r0 + wv * 8 + rr;
        float nf = nodes[(size_t)row * OUTF_ + lane];
        float p1 = nf * a1n + acc[rr] * a1x;
        float p2 = nf * a2n + acc[rr] * a2x;
        #pragma unroll
        for (int off = 32; off; off >>= 1) {
            p1 += __shfl_down(p1, off);
            p2 += __shfl_down(p2, off);
        }
        if (lane == 0) { s1_out[row] = p1; s2_out[row] = p2; }
        t_lds[lane * 40 + wv * 8 + rr] = f2bf(acc[rr]);  // transpose via LDS
    }
    __syncthreads();

    {   // f = output feature row, g = 8-short chunk of the 32 columns
        const int f = tid >> 2, g = tid & 3;
        const int b = r0 >> 11, rb = r0 & (N_ - 1);
        *(uint4*)(xwT + ((size_t)b * OUTF_ + f) * N_ + rb + g * 8) =
            *(const uint4*)&t_lds[f * 40 + g * 8];
    }
}

// Kernel C: 512 threads, 64 rows/block. Wave pairs split the j dimension
// (waves 0-3: j<1024, waves 4-7: j>=1024) -> 2 waves/SIMD. exp2-domain
// softmax: att = exp2(max(c1 + s2L[j], c2 + s2A[j])), all row constants
// (s1, m, -log2 l) folded into c1/c2. Nontemporal stores for att/h.
__global__ __launch_bounds__(512, 2) void attn_kernel(
    const unsigned short* __restrict__ xwT,  // [B][64][N] bf16
    const float* __restrict__ s1g,           // [B, N]
    const float* __restrict__ s2g,           // [B, N]
    float* __restrict__ out_h,               // [B, N, 64] f32
    float* __restrict__ out_att)             // [B, N, N]  f32
{
    __shared__ float s2L[N_];                // s2 * log2e          (8 KB)
    __shared__ float s2A[N_];                // alpha * s2 * log2e  (8 KB)
    __shared__ float s1_lds[64];
    __shared__ float c1_lds[64];
    __shared__ float c2_lds[64];
    __shared__ float redmax[8];
    __shared__ f32x4 redacc[4][64][4];       // 16 KB j-half reduction

    const int tid  = threadIdx.x;
    const int wave = tid >> 6, lane = tid & 63;
    const int b  = blockIdx.x & 7;           // XCD-aware: 1 batch per XCD
    const int i0 = (blockIdx.x >> 3) << 6;

    {   // stage + transform s2, track max
        float4 v = *(const float4*)(s2g + b * N_ + tid * 4);
        float lm = fmaxf(fmaxf(v.x, v.y), fmaxf(v.z, v.w));
        *(float4*)&s2L[tid * 4] = make_float4(v.x * LOG2E, v.y * LOG2E,
                                              v.z * LOG2E, v.w * LOG2E);
        *(float4*)&s2A[tid * 4] = make_float4(v.x * (ALPHA * LOG2E), v.y * (ALPHA * LOG2E),
                                              v.z * (ALPHA * LOG2E), v.w * (ALPHA * LOG2E));
        #pragma unroll
        for (int off = 32; off; off >>= 1) lm = fmaxf(lm, __shfl_xor(lm, off));
        if (lane == 0) redmax[wave] = lm;
    }
    if (tid < 64) s1_lds[tid] = s1g[b * N_ + i0 + tid];
    __syncthreads();

    float s2max = redmax[0];
    #pragma unroll
    for (int w = 1; w < 8; w++) s2max = fmaxf(s2max, redmax[w]);

    // per-row denominator: 8 threads/row, exp2-domain
    {
        const int row = tid >> 3, jo = tid & 7;
        const float s1v = s1_lds[row];
        const float vm  = s1v + s2max;                       // lrelu monotone
        const float mL  = (vm > 0.f ? vm : ALPHA * vm) * LOG2E;
        const float d1  = s1v * LOG2E - mL;
        const float d2  = s1v * (ALPHA * LOG2E) - mL;
        float l = 0.f;
        for (int j = jo * 4; j < N_; j += 32) {
            float4 xl = *(const float4*)&s2L[j];
            float4 xa = *(const float4*)&s2A[j];
            l += __builtin_amdgcn_exp2f(fmaxf(d1 + xl.x, d2 + xa.x));
            l += __builtin_amdgcn_exp2f(fmaxf(d1 + xl.y, d2 + xa.y));
            l += __builtin_amdgcn_exp2f(fmaxf(d1 + xl.z, d2 + xa.z));
            l += __builtin_amdgcn_exp2f(fmaxf(d1 + xl.w, d2 + xa.w));
        }
        l += __shfl_xor(l, 1);
        l += __shfl_xor(l, 2);
        l += __shfl_xor(l, 4);
        if (jo == 0) {
            const float lg = __builtin_amdgcn_logf(l);       // log2(l), l >= 1
            c1_lds[row] = d1 - lg;
            c2_lds[row] = d2 - lg;
        }
    }
    __syncthreads();

    const int row16 = lane & 15;             // MFMA m index
    const int quad  = lane >> 4;             // MFMA k-group
    const int wsub  = wave & 3;
    const int jh    = wave >> 2;             // j-half
    const int irow  = wsub * 16 + row16;
    const float c1  = c1_lds[irow];
    const float c2  = c2_lds[irow];
    const int jb    = jh * 1024;

    const unsigned short* bptr[4];
    #pragma unroll
    for (int g = 0; g < 4; g++)
        bptr[g] = xwT + ((size_t)b * OUTF_ + g * 16 + row16) * N_ + jb + quad * 8;

    float* attp = out_att + ((size_t)(b * N_ + i0 + irow)) * N_ + jb + quad * 8;
    const float* pL = s2L + jb + quad * 8;
    const float* pA = s2A + jb + quad * 8;

    f32x4 acc0 = {0.f,0.f,0.f,0.f}, acc1 = {0.f,0.f,0.f,0.f};
    f32x4 acc2 = {0.f,0.f,0.f,0.f}, acc3 = {0.f,0.f,0.f,0.f};

    uint4 bnext[4];
    #pragma unroll
    for (int g = 0; g < 4; g++) bnext[g] = *(const uint4*)bptr[g];

    for (int jt = 0; jt < 1024; jt += 32) {
        uint4 bc0 = bnext[0], bc1 = bnext[1], bc2 = bnext[2], bc3 = bnext[3];
        const int jn = (jt + 32) & 1023;     // wrap: last prefetch harmless
        #pragma unroll
        for (int g = 0; g < 4; g++) bnext[g] = *(const uint4*)(bptr[g] + jn);

        float4 sa = *(const float4*)(pL + jt);
        float4 sb = *(const float4*)(pL + jt + 4);
        float4 ta = *(const float4*)(pA + jt);
        float4 tb = *(const float4*)(pA + jt + 4);
        float av8[8];
        av8[0] = __builtin_amdgcn_exp2f(fmaxf(c1 + sa.x, c2 + ta.x));
        av8[1] = __builtin_amdgcn_exp2f(fmaxf(c1 + sa.y, c2 + ta.y));
        av8[2] = __builtin_amdgcn_exp2f(fmaxf(c1 + sa.z, c2 + ta.z));
        av8[3] = __builtin_amdgcn_exp2f(fmaxf(c1 + sa.w, c2 + ta.w));
        av8[4] = __builtin_amdgcn_exp2f(fmaxf(c1 + sb.x, c2 + tb.x));
        av8[5] = __builtin_amdgcn_exp2f(fmaxf(c1 + sb.y, c2 + tb.y));
        av8[6] = __builtin_amdgcn_exp2f(fmaxf(c1 + sb.z, c2 + tb.z));
        av8[7] = __builtin_amdgcn_exp2f(fmaxf(c1 + sb.w, c2 + tb.w));

        // fp32 attention out: nontemporal, don't sweep L2
        f32x4 o0 = {av8[0], av8[1], av8[2], av8[3]};
        f32x4 o1 = {av8[4], av8[5], av8[6], av8[7]};
        __builtin_nontemporal_store(o0, (f32x4*)(attp + jt));
        __builtin_nontemporal_store(o1, (f32x4*)(attp + jt + 4));

        short8 a8;
        #pragma unroll
        for (int jj = 0; jj < 8; jj++) a8[jj] = (short)f2bf(av8[jj]);

        acc0 = __builtin_amdgcn_mfma_f32_16x16x32_bf16(a8, *(short8*)&bc0, acc0, 0, 0, 0);
        acc1 = __builtin_amdgcn_mfma_f32_16x16x32_bf16(a8, *(short8*)&bc1, acc1, 0, 0, 0);
        acc2 = __builtin_amdgcn_mfma_f32_16x16x32_bf16(a8, *(short8*)&bc2, acc2, 0, 0, 0);
        acc3 = __builtin_amdgcn_mfma_f32_16x16x32_bf16(a8, *(short8*)&bc3, acc3, 0, 0, 0);
    }

    // combine j-halves: waves 4-7 publish partials, waves 0-3 reduce + store
    if (wave >= 4) {
        redacc[wsub][lane][0] = acc0;
        redacc[wsub][lane][1] = acc1;
        redacc[wsub][lane][2] = acc2;
        redacc[wsub][lane][3] = acc3;
    }
    __syncthreads();
    if (wave < 4) {
        acc0 += redacc[wsub][lane][0];
        acc1 += redacc[wsub][lane][1];
        acc2 += redacc[wsub][lane][2];
        acc3 += redacc[wsub][lane][3];
        const size_t hb = ((size_t)(b * N_) + i0 + wsub * 16) * OUTF_;
        #pragma unroll
        for (int r = 0; r < 4; r++) {
            const size_t ro = hb + (size_t)(quad * 4 + r) * OUTF_ + row16;
            __builtin_nontemporal_store(fmaxf(acc0[r], 0.f), out_h + ro);
            __builtin_nontemporal_store(fmaxf(acc1[r], 0.f), out_h + ro + 16);
            __builtin_nontemporal_store(fmaxf(acc2[r], 0.f), out_h + ro + 32);
            __builtin_nontemporal_store(fmaxf(acc3[r], 0.f), out_h + ro + 48);
        }
    }
}

extern "C" void kernel_launch(void* const* d_in, const int* in_sizes, int n_in,
                              void* d_out, int out_size, void* d_ws, size_t ws_size,
                              hipStream_t stream) {
    const float* inp   = (const float*)d_in[0];
    const float* nodes = (const float*)d_in[1];
    const float* Wm    = (const float*)d_in[2];
    const float* av    = (const float*)d_in[3];

    float* out_h   = (float*)d_out;                                // [8,2048,64]
    float* out_att = out_h + (size_t)B_ * N_ * OUTF_;              // [8,2048,2048]

    // ws: xwT bf16 [8][64][2048] (2 MB) | s1 fp32 (64 KB) | s2 fp32 (64 KB)
    unsigned short* xwT = (unsigned short*)d_ws;
    float* s1_ws = (float*)((char*)d_ws + (size_t)B_ * OUTF_ * N_ * sizeof(unsigned short));
    float* s2_ws = s1_ws + (size_t)B_ * N_;

    prep_kernel<<<(B_ * N_) / 32, 256, 0, stream>>>(inp, nodes, Wm, av,
                                                    xwT, s1_ws, s2_ws);
    attn_kernel<<<256, 512, 0, stream>>>(xwT, s1_ws, s2_ws, out_h, out_att);
}

// Round 3
// 187.169 us; speedup vs baseline: 1.2085x; 1.2085x over previous
//
#include <hip/hip_runtime.h>

#define ALPHA 0.2f
#define B_    8
#define N_    2048
#define INF_  128
#define OUTF_ 64
#define LOG2E 1.4426950408889634f

typedef __attribute__((ext_vector_type(8))) short short8;
typedef __attribute__((ext_vector_type(4))) float f32x4;

__device__ __forceinline__ unsigned short f2bf(float f) {
    unsigned int x = __float_as_uint(f);
    return (unsigned short)((x + 0x7fffu + ((x >> 16) & 1u)) >> 16);
}

// Kernel A (round-0 proven version): x_w = inputs @ W -> xwT (bf16,
// TRANSPOSED [B][64][N]) + s1/s2 row scores. 16 rows/block, 4 rows/wave,
// LDS-broadcast inner loop (no SMEM/LDS lgkmcnt mixing).
__global__ __launch_bounds__(256) void prep_kernel(
    const float* __restrict__ inp,    // [B*N, 128] f32
    const float* __restrict__ nodes,  // [B*N, 64]  f32
    const float* __restrict__ Wm,     // [128, 64]  f32
    const float* __restrict__ av,     // [256]      f32
    unsigned short* __restrict__ xwT, // [B][64][N] bf16
    float* __restrict__ s1_out,       // [B*N]
    float* __restrict__ s2_out)       // [B*N]
{
    __shared__ float w_lds[INF_ * OUTF_];            // 32 KB [k][f]
    __shared__ float in_lds[16 * INF_];              // 8 KB  [r][k]
    __shared__ __align__(16) unsigned short t_lds[64 * 16];  // [n][r] bf16
    const int tid  = threadIdx.x;
    const int wave = tid >> 6, lane = tid & 63;
    const int r0   = blockIdx.x * 16;

    {
        const float4* Wv = (const float4*)Wm;        // 2048 float4
        float4* wd = (float4*)w_lds;
        #pragma unroll
        for (int q = 0; q < 8; q++) wd[tid + q * 256] = Wv[tid + q * 256];
        const float4* Iv = (const float4*)(inp + (size_t)r0 * INF_);  // 512
        float4* id4 = (float4*)in_lds;
        id4[tid]       = Iv[tid];
        id4[tid + 256] = Iv[tid + 256];
    }
    __syncthreads();

    float acc[4] = {0.f, 0.f, 0.f, 0.f};
    const float* inw = &in_lds[(wave * 4) * INF_];
    #pragma unroll 4
    for (int k = 0; k < INF_; k++) {
        float wv = w_lds[k * OUTF_ + lane];     // stride-1 across lanes
        acc[0] += inw[k]            * wv;       // broadcast reads
        acc[1] += inw[INF_ + k]     * wv;
        acc[2] += inw[2 * INF_ + k] * wv;
        acc[3] += inw[3 * INF_ + k] * wv;
    }

    const float a1n = av[lane];
    const float a1x = av[64 + lane];
    const float a2n = av[128 + lane];
    const float a2x = av[192 + lane];

    #pragma unroll
    for (int rr = 0; rr < 4; rr++) {
        const int row = r0 + wave * 4 + rr;
        float nf = nodes[(size_t)row * OUTF_ + lane];
        float p1 = nf * a1n + acc[rr] * a1x;
        float p2 = nf * a2n + acc[rr] * a2x;
        #pragma unroll
        for (int off = 32; off; off >>= 1) {
            p1 += __shfl_down(p1, off);
            p2 += __shfl_down(p2, off);
        }
        if (lane == 0) { s1_out[row] = p1; s2_out[row] = p2; }
        t_lds[lane * 16 + wave * 4 + rr] = f2bf(acc[rr]);  // transpose via LDS
    }
    __syncthreads();

    // thread t writes 4 contiguous bf16 of row n = t>>2 into xwT
    {
        const int n  = tid >> 2, c0 = (tid & 3) * 4;
        const int b  = r0 >> 11, rb = r0 & (N_ - 1);
        *(uint2*)(xwT + ((size_t)b * OUTF_ + n) * N_ + rb + c0) =
            *(const uint2*)&t_lds[n * 16 + c0];
    }
}

// Kernel C: 512 threads, 64 rows/block. Wave pairs split the j dimension
// (waves 0-3: j<1024, waves 4-7: j>=1024) -> 2 waves/SIMD. exp2-domain
// softmax: att = exp2(max(c1 + s2L[j], c2 + s2A[j])), all row constants
// (s1, m, -log2 l) folded into c1/c2. Plain (cached) stores.
__global__ __launch_bounds__(512, 2) void attn_kernel(
    const unsigned short* __restrict__ xwT,  // [B][64][N] bf16
    const float* __restrict__ s1g,           // [B, N]
    const float* __restrict__ s2g,           // [B, N]
    float* __restrict__ out_h,               // [B, N, 64] f32
    float* __restrict__ out_att)             // [B, N, N]  f32
{
    __shared__ float s2L[N_];                // s2 * log2e          (8 KB)
    __shared__ float s2A[N_];                // alpha * s2 * log2e  (8 KB)
    __shared__ float s1_lds[64];
    __shared__ float c1_lds[64];
    __shared__ float c2_lds[64];
    __shared__ float redmax[8];
    __shared__ f32x4 redacc[4][64][4];       // 16 KB j-half reduction

    const int tid  = threadIdx.x;
    const int wave = tid >> 6, lane = tid & 63;
    const int b  = blockIdx.x & 7;           // XCD-aware: 1 batch per XCD
    const int i0 = (blockIdx.x >> 3) << 6;

    {   // stage + transform s2, track max
        float4 v = *(const float4*)(s2g + b * N_ + tid * 4);
        float lm = fmaxf(fmaxf(v.x, v.y), fmaxf(v.z, v.w));
        *(float4*)&s2L[tid * 4] = make_float4(v.x * LOG2E, v.y * LOG2E,
                                              v.z * LOG2E, v.w * LOG2E);
        *(float4*)&s2A[tid * 4] = make_float4(v.x * (ALPHA * LOG2E), v.y * (ALPHA * LOG2E),
                                              v.z * (ALPHA * LOG2E), v.w * (ALPHA * LOG2E));
        #pragma unroll
        for (int off = 32; off; off >>= 1) lm = fmaxf(lm, __shfl_xor(lm, off));
        if (lane == 0) redmax[wave] = lm;
    }
    if (tid < 64) s1_lds[tid] = s1g[b * N_ + i0 + tid];
    __syncthreads();

    float s2max = redmax[0];
    #pragma unroll
    for (int w = 1; w < 8; w++) s2max = fmaxf(s2max, redmax[w]);

    // per-row denominator: 8 threads/row, exp2-domain
    {
        const int row = tid >> 3, jo = tid & 7;
        const float s1v = s1_lds[row];
        const float vm  = s1v + s2max;                       // lrelu monotone
        const float mL  = (vm > 0.f ? vm : ALPHA * vm) * LOG2E;
        const float d1  = s1v * LOG2E - mL;
        const float d2  = s1v * (ALPHA * LOG2E) - mL;
        float l = 0.f;
        for (int j = jo * 4; j < N_; j += 32) {
            float4 xl = *(const float4*)&s2L[j];
            float4 xa = *(const float4*)&s2A[j];
            l += __builtin_amdgcn_exp2f(fmaxf(d1 + xl.x, d2 + xa.x));
            l += __builtin_amdgcn_exp2f(fmaxf(d1 + xl.y, d2 + xa.y));
            l += __builtin_amdgcn_exp2f(fmaxf(d1 + xl.z, d2 + xa.z));
            l += __builtin_amdgcn_exp2f(fmaxf(d1 + xl.w, d2 + xa.w));
        }
        l += __shfl_xor(l, 1);
        l += __shfl_xor(l, 2);
        l += __shfl_xor(l, 4);
        if (jo == 0) {
            const float lg = __builtin_amdgcn_logf(l);       // log2(l), l >= 1
            c1_lds[row] = d1 - lg;
            c2_lds[row] = d2 - lg;
        }
    }
    __syncthreads();

    const int row16 = lane & 15;             // MFMA m index
    const int quad  = lane >> 4;             // MFMA k-group
    const int wsub  = wave & 3;
    const int jh    = wave >> 2;             // j-half
    const int irow  = wsub * 16 + row16;
    const float c1  = c1_lds[irow];
    const float c2  = c2_lds[irow];
    const int jb    = jh * 1024;

    const unsigned short* bptr[4];
    #pragma unroll
    for (int g = 0; g < 4; g++)
        bptr[g] = xwT + ((size_t)b * OUTF_ + g * 16 + row16) * N_ + jb + quad * 8;

    float* attp = out_att + ((size_t)(b * N_ + i0 + irow)) * N_ + jb + quad * 8;
    const float* pL = s2L + jb + quad * 8;
    const float* pA = s2A + jb + quad * 8;

    f32x4 acc0 = {0.f,0.f,0.f,0.f}, acc1 = {0.f,0.f,0.f,0.f};
    f32x4 acc2 = {0.f,0.f,0.f,0.f}, acc3 = {0.f,0.f,0.f,0.f};

    uint4 bnext[4];
    #pragma unroll
    for (int g = 0; g < 4; g++) bnext[g] = *(const uint4*)bptr[g];

    for (int jt = 0; jt < 1024; jt += 32) {
        uint4 bc0 = bnext[0], bc1 = bnext[1], bc2 = bnext[2], bc3 = bnext[3];
        const int jn = (jt + 32) & 1023;     // wrap: last prefetch harmless
        #pragma unroll
        for (int g = 0; g < 4; g++) bnext[g] = *(const uint4*)(bptr[g] + jn);

        float4 sa = *(const float4*)(pL + jt);
        float4 sb = *(const float4*)(pL + jt + 4);
        float4 ta = *(const float4*)(pA + jt);
        float4 tb = *(const float4*)(pA + jt + 4);
        float av8[8];
        av8[0] = __builtin_amdgcn_exp2f(fmaxf(c1 + sa.x, c2 + ta.x));
        av8[1] = __builtin_amdgcn_exp2f(fmaxf(c1 + sa.y, c2 + ta.y));
        av8[2] = __builtin_amdgcn_exp2f(fmaxf(c1 + sa.z, c2 + ta.z));
        av8[3] = __builtin_amdgcn_exp2f(fmaxf(c1 + sa.w, c2 + ta.w));
        av8[4] = __builtin_amdgcn_exp2f(fmaxf(c1 + sb.x, c2 + tb.x));
        av8[5] = __builtin_amdgcn_exp2f(fmaxf(c1 + sb.y, c2 + tb.y));
        av8[6] = __builtin_amdgcn_exp2f(fmaxf(c1 + sb.z, c2 + tb.z));
        av8[7] = __builtin_amdgcn_exp2f(fmaxf(c1 + sb.w, c2 + tb.w));

        // fp32 attention out: plain cached stores (NT regressed in R1)
        *(float4*)(attp + jt)     = make_float4(av8[0], av8[1], av8[2], av8[3]);
        *(float4*)(attp + jt + 4) = make_float4(av8[4], av8[5], av8[6], av8[7]);

        short8 a8;
        #pragma unroll
        for (int jj = 0; jj < 8; jj++) a8[jj] = (short)f2bf(av8[jj]);

        acc0 = __builtin_amdgcn_mfma_f32_16x16x32_bf16(a8, *(short8*)&bc0, acc0, 0, 0, 0);
        acc1 = __builtin_amdgcn_mfma_f32_16x16x32_bf16(a8, *(short8*)&bc1, acc1, 0, 0, 0);
        acc2 = __builtin_amdgcn_mfma_f32_16x16x32_bf16(a8, *(short8*)&bc2, acc2, 0, 0, 0);
        acc3 = __builtin_amdgcn_mfma_f32_16x16x32_bf16(a8, *(short8*)&bc3, acc3, 0, 0, 0);
    }

    // combine j-halves: waves 4-7 publish partials, waves 0-3 reduce + store
    if (wave >= 4) {
        redacc[wsub][lane][0] = acc0;
        redacc[wsub][lane][1] = acc1;
        redacc[wsub][lane][2] = acc2;
        redacc[wsub][lane][3] = acc3;
    }
    __syncthreads();
    if (wave < 4) {
        acc0 += redacc[wsub][lane][0];
        acc1 += redacc[wsub][lane][1];
        acc2 += redacc[wsub][lane][2];
        acc3 += redacc[wsub][lane][3];
        const size_t hb = ((size_t)(b * N_) + i0 + wsub * 16) * OUTF_;
        #pragma unroll
        for (int r = 0; r < 4; r++) {
            const size_t ro = hb + (size_t)(quad * 4 + r) * OUTF_ + row16;
            out_h[ro]      = fmaxf(acc0[r], 0.f);
            out_h[ro + 16] = fmaxf(acc1[r], 0.f);
            out_h[ro + 32] = fmaxf(acc2[r], 0.f);
            out_h[ro + 48] = fmaxf(acc3[r], 0.f);
        }
    }
}

extern "C" void kernel_launch(void* const* d_in, const int* in_sizes, int n_in,
                              void* d_out, int out_size, void* d_ws, size_t ws_size,
                              hipStream_t stream) {
    const float* inp   = (const float*)d_in[0];
    const float* nodes = (const float*)d_in[1];
    const float* Wm    = (const float*)d_in[2];
    const float* av    = (const float*)d_in[3];

    float* out_h   = (float*)d_out;                                // [8,2048,64]
    float* out_att = out_h + (size_t)B_ * N_ * OUTF_;              // [8,2048,2048]

    // ws: xwT bf16 [8][64][2048] (2 MB) | s1 fp32 (64 KB) | s2 fp32 (64 KB)
    unsigned short* xwT = (unsigned short*)d_ws;
    float* s1_ws = (float*)((char*)d_ws + (size_t)B_ * OUTF_ * N_ * sizeof(unsigned short));
    float* s2_ws = s1_ws + (size_t)B_ * N_;

    prep_kernel<<<(B_ * N_) / 16, 256, 0, stream>>>(inp, nodes, Wm, av,
                                                    xwT, s1_ws, s2_ws);
    attn_kernel<<<256, 512, 0, stream>>>(xwT, s1_ws, s2_ws, out_h, out_att);
}